// Round 3
// baseline (160.621 us; speedup 1.0000x reference)
//
#include <hip/hip_runtime.h>
#include <hip/hip_bf16.h>

typedef __attribute__((ext_vector_type(8))) short short8;
typedef __attribute__((ext_vector_type(4))) float f32x4;
typedef __attribute__((ext_vector_type(8))) unsigned short ushort8;

__device__ __forceinline__ float bf2f(unsigned short u) {
  union { unsigned int i; float f; } v;
  v.i = ((unsigned int)u) << 16;
  return v.f;
}

__device__ __forceinline__ unsigned short f2bf(float f) {
  union { float f; unsigned int i; } v;
  v.f = f;
  unsigned int x = v.i;
  return (unsigned short)((x + 0x7FFFu + ((x >> 16) & 1u)) >> 16);
}

__device__ __forceinline__ void async_load16(const void* g, void* l) {
  __builtin_amdgcn_global_load_lds(
      (const __attribute__((address_space(1))) unsigned int*)g,
      (__attribute__((address_space(3))) unsigned int*)l, 16, 0, 0);
}

// ---------------------------------------------------------------------------
// Kernel 1: fc1w f32 -> bf16 with k-permutation k' = p*64 + c2  (k = c2*36+p)
// ---------------------------------------------------------------------------
__global__ __launch_bounds__(256) void cvt_permute(
    const float* __restrict__ fc1, unsigned short* __restrict__ out) {
  __shared__ float row[2304];
  const int n = blockIdx.x;
  const float* src = fc1 + (size_t)n * 2304;
  for (int i = threadIdx.x; i < 2304; i += 256) row[i] = src[i];
  __syncthreads();
  unsigned short* dst = out + (size_t)n * 2304;
  for (int i = threadIdx.x; i < 2304; i += 256) {
    int pp = i >> 6, c2 = i & 63;
    dst[i] = f2bf(row[c2 * 36 + pp]);
  }
}

// ---------------------------------------------------------------------------
// Kernel 2: fused conv1+conv2 as 36 x (B/64) micro-GEMMs via MFMA.
// out2 layout: [B][k'] with k' = p*64 + c2.
// ---------------------------------------------------------------------------
#define LDP 72
__global__ __launch_bounds__(256) void conv_fused2(
    const float* __restrict__ x, const float* __restrict__ w1,
    const float* __restrict__ w2, unsigned short* __restrict__ out2, int B) {
  __shared__ unsigned short s_w2[64 * LDP];
  __shared__ unsigned short s_win[64 * LDP];
  const int tid = threadIdx.x;
  const int b0 = blockIdx.x * 64;
  const int p = blockIdx.y;
  const int u = p / 6, u2 = p % 6;

  const float* w2p = w2 + (size_t)p * 48;
  for (int i = tid; i < 64 * 64; i += 256) {
    int c2 = i >> 6, kk = i & 63;
    float v = (kk < 48) ? w2p[(size_t)c2 * 1728 + kk] : 0.f;
    s_w2[c2 * LDP + kk] = f2bf(v);
  }
  for (int i = tid; i < 64 * 64; i += 256) {
    int bi = i >> 6, kk = i & 63;
    float a = 0.f;
    if (kk < 48) {
      int c = kk >> 4, rem = kk & 15, v = rem >> 2, v2 = rem & 3;
      int pi = 2 * u + v, pj = 2 * u2 + v2;
      const float* wr = w1 + (((c * 196) + pi * 14 + pj) << 2);
      const float* xb = x + (size_t)(b0 + bi) * 784 + pi * 56 + pj * 2;
      a = fmaxf(xb[0] * wr[0] + xb[1] * wr[1] + xb[28] * wr[2] + xb[29] * wr[3],
                0.f);
    }
    s_win[bi * LDP + kk] = f2bf(a);
  }
  __syncthreads();

  const int lane = tid & 63, wave = tid >> 6;
  const int wm = wave >> 1, wn = wave & 1;
  const int fr = lane & 15, fo = (lane >> 4) * 8;
  f32x4 acc[2][2] = {};
  #pragma unroll
  for (int k2 = 0; k2 < 2; ++k2) {
    short8 af[2], bf[2];
    #pragma unroll
    for (int m = 0; m < 2; ++m)
      af[m] = *(const short8*)&s_win[(wm * 32 + m * 16 + fr) * LDP + k2 * 32 + fo];
    #pragma unroll
    for (int n = 0; n < 2; ++n)
      bf[n] = *(const short8*)&s_w2[(wn * 32 + n * 16 + fr) * LDP + k2 * 32 + fo];
    #pragma unroll
    for (int m = 0; m < 2; ++m)
      #pragma unroll
      for (int n = 0; n < 2; ++n)
        acc[m][n] =
            __builtin_amdgcn_mfma_f32_16x16x32_bf16(af[m], bf[n], acc[m][n], 0, 0, 0);
  }

  const int r0 = wm * 32 + (lane >> 4) * 4;
  const int c0 = wn * 32 + fr;
  #pragma unroll
  for (int m = 0; m < 2; ++m)
    #pragma unroll
    for (int n = 0; n < 2; ++n)
      #pragma unroll
      for (int j = 0; j < 4; ++j) {
        int bi = r0 + m * 16 + j;
        int c2 = c0 + n * 16;
        out2[(size_t)(b0 + bi) * 2304 + p * 64 + c2] =
            f2bf(fmaxf(acc[m][n][j], 0.f));
      }
}

// ---------------------------------------------------------------------------
// Kernel 3: fused  h = relu(out2 @ fc1b^T)  and  out += h @ fc2w^T.
// BM=256, BN=128, BK=64, 512 threads (8 waves 4x2, 64x64 out per wave).
// Triple-buffered LDS, counted vmcnt(6), 2 phases/K-step, T2 XOR swizzle.
// ---------------------------------------------------------------------------
#define GBM 256
#define GBN 128
#define GBK 64

__global__ __launch_bounds__(512) void gemm_fc1_fc2(
    const unsigned short* __restrict__ A,   // [M][K] out2 bf16 (k' order)
    const unsigned short* __restrict__ Bw,  // [N][K] fc1b bf16 (k' order)
    const float* __restrict__ Wfc2,         // [10][1024] f32
    float* __restrict__ out,                // [M][10] f32 (pre-zeroed)
    int K, int NT) {
  __shared__ unsigned short sA[3 * GBM * GBK];  // 96 KiB
  __shared__ unsigned short sB[3 * GBN * GBK];  // 48 KiB
  __shared__ float sW[10 * GBN];                // 5 KiB
  const int tid = threadIdx.x;
  const int lane = tid & 63;
  const int wave = tid >> 6;
  const int wm = wave >> 1, wn = wave & 1;  // 4 x 2 wave grid
  const size_t m0 = (size_t)blockIdx.x * GBM;
  const size_t n0 = (size_t)blockIdx.y * GBN;

  // stage fc2 W slice for this block's 128 cols
  for (int i = tid; i < 10 * GBN; i += 512)
    sW[i] = Wfc2[(i >> 7) * 1024 + n0 + (i & 127)];

  // --- staging geometry (T2: source-side XOR swizzle, linear LDS dest) ---
  const int r8 = tid >> 3;            // 0..63 (row within 64-row round)
  const int c8 = tid & 7;             // 16B chunk 0..7
  const int ksw = (c8 ^ (r8 & 7)) * 8;  // swizzled source k-chunk (elements)
  const unsigned short* Ag = A + (m0 + r8) * (size_t)K + ksw;
  const unsigned short* Bg = Bw + (n0 + r8) * (size_t)K + ksw;
  unsigned short* sAp = &sA[r8 * GBK + c8 * 8];
  unsigned short* sBp = &sB[r8 * GBK + c8 * 8];

#define STAGE_A(buf, t, i) \
  async_load16(Ag + (size_t)(t) * GBK + (size_t)(i) * 64 * K, \
               sAp + (buf) * GBM * GBK + (i) * 64 * GBK)
#define STAGE_B(buf, t, i) \
  async_load16(Bg + (size_t)(t) * GBK + (size_t)(i) * 64 * K, \
               sBp + (buf) * GBN * GBK + (i) * 64 * GBK)

  // prologue: tiles 0 and 1 in flight (6 loads each)
  STAGE_A(0, 0, 0); STAGE_A(0, 0, 1); STAGE_A(0, 0, 2); STAGE_A(0, 0, 3);
  STAGE_B(0, 0, 0); STAGE_B(0, 0, 1);
  STAGE_A(1, 1, 0); STAGE_A(1, 1, 1); STAGE_A(1, 1, 2); STAGE_A(1, 1, 3);
  STAGE_B(1, 1, 0); STAGE_B(1, 1, 1);

  // --- fragment read geometry ---
  const int fr = lane & 15, fg = lane >> 4, fx = lane & 7;
  int aBase[4], bBase[4];
  #pragma unroll
  for (int m = 0; m < 4; ++m) aBase[m] = (wm * 64 + m * 16 + fr) * GBK;
  #pragma unroll
  for (int n = 0; n < 4; ++n) bBase[n] = (wn * 64 + n * 16 + fr) * GBK;
  const int jc0 = ((fg ^ fx) * 8);      // ks=0 swizzled chunk offset (ushorts)
  const int jc1 = jc0 ^ 32;             // ks=1 ( (4+fg)^fx = (fg^fx)^4 )

  f32x4 acc[4][4] = {};

  for (int t = 0; t < NT; ++t) {
    const int cb = t - (t / 3) * 3;
    const unsigned short* As = &sA[cb * GBM * GBK];
    const unsigned short* Bs = &sB[cb * GBN * GBK];
    if (t == NT - 1) {
      asm volatile("s_waitcnt vmcnt(0)" ::: "memory");
    } else {
      asm volatile("s_waitcnt vmcnt(6)" ::: "memory");
    }
    __builtin_amdgcn_s_barrier();  // all waves' tile-t slices landed

    const int t2 = t + 2;
    const int sb = t2 - (t2 / 3) * 3;
    const bool st = t2 < NT;

    // ---- phase 0 (ksub = 0) ----
    short8 af[4], bfr[4];
    #pragma unroll
    for (int m = 0; m < 4; ++m) af[m] = *(const short8*)&As[aBase[m] + jc0];
    #pragma unroll
    for (int n = 0; n < 4; ++n) bfr[n] = *(const short8*)&Bs[bBase[n] + jc0];
    if (st) { STAGE_A(sb, t2, 0); STAGE_A(sb, t2, 1); STAGE_A(sb, t2, 2); }
    __builtin_amdgcn_s_barrier();
    asm volatile("s_waitcnt lgkmcnt(0)" ::: "memory");
    __builtin_amdgcn_sched_barrier(0);
    __builtin_amdgcn_s_setprio(1);
    #pragma unroll
    for (int m = 0; m < 4; ++m)
      #pragma unroll
      for (int n = 0; n < 4; ++n)
        acc[m][n] = __builtin_amdgcn_mfma_f32_16x16x32_bf16(af[m], bfr[n],
                                                            acc[m][n], 0, 0, 0);
    __builtin_amdgcn_s_setprio(0);
    __builtin_amdgcn_s_barrier();

    // ---- phase 1 (ksub = 1) ----
    #pragma unroll
    for (int m = 0; m < 4; ++m) af[m] = *(const short8*)&As[aBase[m] + jc1];
    #pragma unroll
    for (int n = 0; n < 4; ++n) bfr[n] = *(const short8*)&Bs[bBase[n] + jc1];
    if (st) { STAGE_A(sb, t2, 3); STAGE_B(sb, t2, 0); STAGE_B(sb, t2, 1); }
    __builtin_amdgcn_s_barrier();
    asm volatile("s_waitcnt lgkmcnt(0)" ::: "memory");
    __builtin_amdgcn_sched_barrier(0);
    __builtin_amdgcn_s_setprio(1);
    #pragma unroll
    for (int m = 0; m < 4; ++m)
      #pragma unroll
      for (int n = 0; n < 4; ++n)
        acc[m][n] = __builtin_amdgcn_mfma_f32_16x16x32_bf16(af[m], bfr[n],
                                                            acc[m][n], 0, 0, 0);
    __builtin_amdgcn_s_setprio(0);
    __builtin_amdgcn_s_barrier();
  }

  // ---- epilogue: relu -> bf16 h-tile into LDS (swizzled), then fused fc2 ----
  unsigned short* hs = sA;  // 256*128 ushorts = 64 KiB, staging is dead now
  #pragma unroll
  for (int m = 0; m < 4; ++m)
    #pragma unroll
    for (int n = 0; n < 4; ++n)
      #pragma unroll
      for (int j = 0; j < 4; ++j) {
        int row = wm * 64 + m * 16 + fg * 4 + j;  // 0..255
        int col = wn * 64 + n * 16 + fr;          // 0..127
        hs[row * 128 + (col ^ ((row & 7) << 3))] =
            f2bf(fmaxf(acc[m][n][j], 0.f));
      }
  __syncthreads();

  {
    const int row = tid >> 1;       // 0..255
    const int half = tid & 1;       // col half
    const int r7s = (row & 7) << 3;
    float hv[64];
    #pragma unroll
    for (int c = 0; c < 8; ++c) {
      int base = half * 64 + c * 8;
      short8 u = *(const short8*)&hs[row * 128 + (base ^ r7s)];
      #pragma unroll
      for (int q = 0; q < 8; ++q) hv[c * 8 + q] = bf2f((unsigned short)u[q]);
    }
    float* op = out + (m0 + row) * 10;
    #pragma unroll
    for (int o = 0; o < 10; ++o) {
      const float* wr = &sW[o * 128 + half * 64];
      float a = 0.f;
      #pragma unroll
      for (int q = 0; q < 64; ++q) a += hv[q] * wr[q];
      atomicAdd(&op[o], a);
    }
  }
#undef STAGE_A
#undef STAGE_B
}

// ---------------------------------------------------------------------------
extern "C" void kernel_launch(void* const* d_in, const int* in_sizes, int n_in,
                              void* d_out, int out_size, void* d_ws, size_t ws_size,
                              hipStream_t stream) {
  const float* x   = (const float*)d_in[0];
  const float* w1  = (const float*)d_in[1];
  const float* w2  = (const float*)d_in[2];
  const float* fc1 = (const float*)d_in[3];
  const float* fc2 = (const float*)d_in[4];
  float* out = (float*)d_out;
  const int B = in_sizes[0] / 784;  // 8192

  unsigned short* out2 = (unsigned short*)d_ws;       // B*2304 bf16
  unsigned short* fc1b = out2 + (size_t)B * 2304;     // 1024*2304 bf16

  hipMemsetAsync(out, 0, (size_t)out_size * sizeof(float), stream);
  cvt_permute<<<1024, 256, 0, stream>>>(fc1, fc1b);
  dim3 cg(B / 64, 36);
  conv_fused2<<<cg, 256, 0, stream>>>(x, w1, w2, out2, B);
  dim3 g(B / GBM, 1024 / GBN);
  gemm_fc1_fc2<<<g, 512, 0, stream>>>(out2, fc1b, fc2, out, 2304, 2304 / GBK);
}

// Round 4
// 121.727 us; speedup vs baseline: 1.3195x; 1.3195x over previous
//
#include <hip/hip_runtime.h>
#include <hip/hip_bf16.h>

typedef __attribute__((ext_vector_type(8))) short short8;
typedef __attribute__((ext_vector_type(4))) float f32x4;
typedef __attribute__((ext_vector_type(8))) unsigned short ushort8;

__device__ __forceinline__ float bf2f(unsigned short u) {
  union { unsigned int i; float f; } v;
  v.i = ((unsigned int)u) << 16;
  return v.f;
}

__device__ __forceinline__ unsigned short f2bf(float f) {
  union { float f; unsigned int i; } v;
  v.f = f;
  unsigned int x = v.i;
  return (unsigned short)((x + 0x7FFFu + ((x >> 16) & 1u)) >> 16);
}

__device__ __forceinline__ void async_load16(const void* g, void* l) {
  __builtin_amdgcn_global_load_lds(
      (const __attribute__((address_space(1))) unsigned int*)g,
      (__attribute__((address_space(3))) unsigned int*)l, 16, 0, 0);
}

// ---------------------------------------------------------------------------
// Kernel 1: fc1w f32 -> bf16 with k-permutation k' = p*64 + c2  (k = c2*36+p)
// ---------------------------------------------------------------------------
__global__ __launch_bounds__(256) void cvt_permute(
    const float* __restrict__ fc1, unsigned short* __restrict__ out) {
  __shared__ float row[2304];
  const int n = blockIdx.x;
  const float* src = fc1 + (size_t)n * 2304;
  for (int i = threadIdx.x; i < 2304; i += 256) row[i] = src[i];
  __syncthreads();
  unsigned short* dst = out + (size_t)n * 2304;
  for (int i = threadIdx.x; i < 2304; i += 256) {
    int pp = i >> 6, c2 = i & 63;
    dst[i] = f2bf(row[c2 * 36 + pp]);
  }
}

// ---------------------------------------------------------------------------
// Kernel 2: fused conv1+conv2 as 36 x (B/64) micro-GEMMs via MFMA.
// out2 layout: [B][k'] with k' = p*64 + c2.
// ---------------------------------------------------------------------------
#define LDP 72
__global__ __launch_bounds__(256) void conv_fused2(
    const float* __restrict__ x, const float* __restrict__ w1,
    const float* __restrict__ w2, unsigned short* __restrict__ out2, int B) {
  __shared__ unsigned short s_w2[64 * LDP];
  __shared__ unsigned short s_win[64 * LDP];
  const int tid = threadIdx.x;
  const int b0 = blockIdx.x * 64;
  const int p = blockIdx.y;
  const int u = p / 6, u2 = p % 6;

  const float* w2p = w2 + (size_t)p * 48;
  for (int i = tid; i < 64 * 64; i += 256) {
    int c2 = i >> 6, kk = i & 63;
    float v = (kk < 48) ? w2p[(size_t)c2 * 1728 + kk] : 0.f;
    s_w2[c2 * LDP + kk] = f2bf(v);
  }
  for (int i = tid; i < 64 * 64; i += 256) {
    int bi = i >> 6, kk = i & 63;
    float a = 0.f;
    if (kk < 48) {
      int c = kk >> 4, rem = kk & 15, v = rem >> 2, v2 = rem & 3;
      int pi = 2 * u + v, pj = 2 * u2 + v2;
      const float* wr = w1 + (((c * 196) + pi * 14 + pj) << 2);
      const float* xb = x + (size_t)(b0 + bi) * 784 + pi * 56 + pj * 2;
      a = fmaxf(xb[0] * wr[0] + xb[1] * wr[1] + xb[28] * wr[2] + xb[29] * wr[3],
                0.f);
    }
    s_win[bi * LDP + kk] = f2bf(a);
  }
  __syncthreads();

  const int lane = tid & 63, wave = tid >> 6;
  const int wm = wave >> 1, wn = wave & 1;
  const int fr = lane & 15, fo = (lane >> 4) * 8;
  f32x4 acc[2][2] = {};
  #pragma unroll
  for (int k2 = 0; k2 < 2; ++k2) {
    short8 af[2], bf[2];
    #pragma unroll
    for (int m = 0; m < 2; ++m)
      af[m] = *(const short8*)&s_win[(wm * 32 + m * 16 + fr) * LDP + k2 * 32 + fo];
    #pragma unroll
    for (int n = 0; n < 2; ++n)
      bf[n] = *(const short8*)&s_w2[(wn * 32 + n * 16 + fr) * LDP + k2 * 32 + fo];
    #pragma unroll
    for (int m = 0; m < 2; ++m)
      #pragma unroll
      for (int n = 0; n < 2; ++n)
        acc[m][n] =
            __builtin_amdgcn_mfma_f32_16x16x32_bf16(af[m], bf[n], acc[m][n], 0, 0, 0);
  }

  const int r0 = wm * 32 + (lane >> 4) * 4;
  const int c0 = wn * 32 + fr;
  #pragma unroll
  for (int m = 0; m < 2; ++m)
    #pragma unroll
    for (int n = 0; n < 2; ++n)
      #pragma unroll
      for (int j = 0; j < 4; ++j) {
        int bi = r0 + m * 16 + j;
        int c2 = c0 + n * 16;
        out2[(size_t)(b0 + bi) * 2304 + p * 64 + c2] =
            f2bf(fmaxf(acc[m][n][j], 0.f));
      }
}

// ---------------------------------------------------------------------------
// Kernel 3: fused  h = relu(out2 @ fc1b^T)  and  out += h @ fc2w^T.
// BM=BN=128, BK=64, 256 threads (4 waves 2x2, 64x64 out per wave).
// Double-buffered LDS (64 KB -> 2 blocks/CU), counted vmcnt(8),
// ONE barrier-pair per K-tile, T2 source-side XOR swizzle.
// ---------------------------------------------------------------------------
#define GBM 128
#define GBN 128
#define GBK 64

__global__ __launch_bounds__(256) void gemm_fc1_fc2(
    const unsigned short* __restrict__ A,   // [M][K] out2 bf16 (k' order)
    const unsigned short* __restrict__ Bw,  // [N][K] fc1b bf16 (k' order)
    const float* __restrict__ Wfc2,         // [10][1024] f32
    float* __restrict__ out,                // [M][10] f32 (pre-zeroed)
    int K, int NT) {
  __shared__ unsigned short sA[2 * GBM * GBK];  // 32 KiB
  __shared__ unsigned short sB[2 * GBN * GBK];  // 32 KiB
  __shared__ float sW[10 * GBN];                // 5 KiB
  const int tid = threadIdx.x;
  const int lane = tid & 63;
  const int wave = tid >> 6;
  const int wm = wave >> 1, wn = wave & 1;  // 2 x 2 wave grid
  const size_t m0 = (size_t)blockIdx.x * GBM;
  const size_t n0 = (size_t)blockIdx.y * GBN;

  for (int i = tid; i < 10 * GBN; i += 256)
    sW[i] = Wfc2[(i >> 7) * 1024 + n0 + (i & 127)];

  // --- staging geometry (T2: source-side XOR swizzle, linear LDS dest) ---
  const int r8 = tid >> 3;               // 0..31 (row within 32-row round)
  const int c8 = tid & 7;                // 16B chunk 0..7
  const int ksw = (c8 ^ (r8 & 7)) * 8;   // swizzled source k-chunk (elements)
  const unsigned short* Ag = A + (m0 + r8) * (size_t)K + ksw;
  const unsigned short* Bg = Bw + (n0 + r8) * (size_t)K + ksw;
  unsigned short* sAp = &sA[r8 * GBK + c8 * 8];
  unsigned short* sBp = &sB[r8 * GBK + c8 * 8];

#define STAGE_A(buf, t, i) \
  async_load16(Ag + (size_t)(t) * GBK + (size_t)(i) * 32 * K, \
               sAp + (buf) * (GBM * GBK) + (i) * 32 * GBK)
#define STAGE_B(buf, t, i) \
  async_load16(Bg + (size_t)(t) * GBK + (size_t)(i) * 32 * K, \
               sBp + (buf) * (GBN * GBK) + (i) * 32 * GBK)
#define STAGE_TILE(buf, t) \
  STAGE_A(buf, t, 0); STAGE_A(buf, t, 1); STAGE_A(buf, t, 2); STAGE_A(buf, t, 3); \
  STAGE_B(buf, t, 0); STAGE_B(buf, t, 1); STAGE_B(buf, t, 2); STAGE_B(buf, t, 3)

  // prologue: tile 0 in flight
  STAGE_TILE(0, 0);

  // --- fragment read geometry ---
  const int fr = lane & 15, fg = lane >> 4, fx = lane & 7;
  int aBase[4], bBase[4];
  #pragma unroll
  for (int m = 0; m < 4; ++m) aBase[m] = (wm * 64 + m * 16 + fr) * GBK;
  #pragma unroll
  for (int n = 0; n < 4; ++n) bBase[n] = (wn * 64 + n * 16 + fr) * GBK;
  const int jc0 = (fg ^ fx) * 8;  // ks=0 swizzled chunk offset (ushorts)
  const int jc1 = jc0 ^ 32;       // ks=1

  f32x4 acc[4][4] = {};

  for (int t = 0; t < NT; ++t) {
    const int cur = t & 1;
    if (t + 1 < NT) {
      STAGE_TILE(cur ^ 1, t + 1);              // prefetch next tile
      asm volatile("s_waitcnt vmcnt(8)" ::: "memory");  // drain tile t only
    } else {
      asm volatile("s_waitcnt vmcnt(0)" ::: "memory");
    }
    __builtin_amdgcn_s_barrier();  // tile t visible to all waves

    const unsigned short* As = &sA[cur * GBM * GBK];
    const unsigned short* Bs = &sB[cur * GBN * GBK];
    short8 a0[4], b0[4], a1[4], b1[4];
    #pragma unroll
    for (int m = 0; m < 4; ++m) {
      a0[m] = *(const short8*)&As[aBase[m] + jc0];
      a1[m] = *(const short8*)&As[aBase[m] + jc1];
    }
    #pragma unroll
    for (int n = 0; n < 4; ++n) {
      b0[n] = *(const short8*)&Bs[bBase[n] + jc0];
      b1[n] = *(const short8*)&Bs[bBase[n] + jc1];
    }
    __builtin_amdgcn_s_setprio(1);
    #pragma unroll
    for (int m = 0; m < 4; ++m)
      #pragma unroll
      for (int n = 0; n < 4; ++n)
        acc[m][n] = __builtin_amdgcn_mfma_f32_16x16x32_bf16(a0[m], b0[n],
                                                            acc[m][n], 0, 0, 0);
    #pragma unroll
    for (int m = 0; m < 4; ++m)
      #pragma unroll
      for (int n = 0; n < 4; ++n)
        acc[m][n] = __builtin_amdgcn_mfma_f32_16x16x32_bf16(a1[m], b1[n],
                                                            acc[m][n], 0, 0, 0);
    __builtin_amdgcn_s_setprio(0);
    __builtin_amdgcn_s_barrier();  // all waves done reading buffer cur
  }

  // ---- epilogue: relu -> bf16 h-tile into LDS (swizzled), then fused fc2 ----
  unsigned short* hs = sA;  // 128*128 ushorts = 32 KiB, staging is dead now
  #pragma unroll
  for (int m = 0; m < 4; ++m)
    #pragma unroll
    for (int n = 0; n < 4; ++n)
      #pragma unroll
      for (int j = 0; j < 4; ++j) {
        int row = wm * 64 + m * 16 + fg * 4 + j;  // 0..127
        int col = wn * 64 + n * 16 + fr;          // 0..127
        hs[row * 128 + (col ^ ((row & 7) << 3))] =
            f2bf(fmaxf(acc[m][n][j], 0.f));
      }
  __syncthreads();

  {
    const int row = tid >> 1;   // 0..127
    const int half = tid & 1;   // col half
    const int r7s = (row & 7) << 3;
    float hv[64];
    #pragma unroll
    for (int c = 0; c < 8; ++c) {
      int base = half * 64 + c * 8;
      short8 u = *(const short8*)&hs[row * 128 + (base ^ r7s)];
      #pragma unroll
      for (int q = 0; q < 8; ++q) hv[c * 8 + q] = bf2f((unsigned short)u[q]);
    }
    float* op = out + (m0 + row) * 10;
    #pragma unroll
    for (int o = 0; o < 10; ++o) {
      const float* wr = &sW[o * 128 + half * 64];
      float a = 0.f;
      #pragma unroll
      for (int q = 0; q < 64; ++q) a += hv[q] * wr[q];
      a += __shfl_down(a, 1);           // combine the two halves
      if (half == 0) atomicAdd(&op[o], a);
    }
  }
#undef STAGE_A
#undef STAGE_B
#undef STAGE_TILE
}

// ---------------------------------------------------------------------------
extern "C" void kernel_launch(void* const* d_in, const int* in_sizes, int n_in,
                              void* d_out, int out_size, void* d_ws, size_t ws_size,
                              hipStream_t stream) {
  const float* x   = (const float*)d_in[0];
  const float* w1  = (const float*)d_in[1];
  const float* w2  = (const float*)d_in[2];
  const float* fc1 = (const float*)d_in[3];
  const float* fc2 = (const float*)d_in[4];
  float* out = (float*)d_out;
  const int B = in_sizes[0] / 784;  // 8192

  unsigned short* out2 = (unsigned short*)d_ws;       // B*2304 bf16
  unsigned short* fc1b = out2 + (size_t)B * 2304;     // 1024*2304 bf16

  hipMemsetAsync(out, 0, (size_t)out_size * sizeof(float), stream);
  cvt_permute<<<1024, 256, 0, stream>>>(fc1, fc1b);
  dim3 cg(B / 64, 36);
  conv_fused2<<<cg, 256, 0, stream>>>(x, w1, w2, out2, B);
  dim3 g(B / GBM, 1024 / GBN);
  gemm_fc1_fc2<<<g, 256, 0, stream>>>(out2, fc1b, fc2, out, 2304, 2304 / GBK);
}

// Round 5
// 119.416 us; speedup vs baseline: 1.3451x; 1.0194x over previous
//
#include <hip/hip_runtime.h>
#include <hip/hip_bf16.h>

typedef __attribute__((ext_vector_type(8))) short short8;
typedef __attribute__((ext_vector_type(4))) float f32x4;
typedef __attribute__((ext_vector_type(8))) unsigned short ushort8;

__device__ __forceinline__ float bf2f(unsigned short u) {
  union { unsigned int i; float f; } v;
  v.i = ((unsigned int)u) << 16;
  return v.f;
}

__device__ __forceinline__ unsigned short f2bf(float f) {
  union { float f; unsigned int i; } v;
  v.f = f;
  unsigned int x = v.i;
  return (unsigned short)((x + 0x7FFFu + ((x >> 16) & 1u)) >> 16);
}

__device__ __forceinline__ void async_load16(const void* g, void* l) {
  __builtin_amdgcn_global_load_lds(
      (const __attribute__((address_space(1))) unsigned int*)g,
      (__attribute__((address_space(3))) unsigned int*)l, 16, 0, 0);
}

// ---------------------------------------------------------------------------
// Kernel 1: fc1w f32 -> bf16 with k-permutation k' = p*64 + c2  (k = c2*36+p)
// ---------------------------------------------------------------------------
__global__ __launch_bounds__(256) void cvt_permute(
    const float* __restrict__ fc1, unsigned short* __restrict__ out) {
  __shared__ float row[2304];
  const int n = blockIdx.x;
  const float* src = fc1 + (size_t)n * 2304;
  for (int i = threadIdx.x; i < 2304; i += 256) row[i] = src[i];
  __syncthreads();
  unsigned short* dst = out + (size_t)n * 2304;
  for (int i = threadIdx.x; i < 2304; i += 256) {
    int pp = i >> 6, c2 = i & 63;
    dst[i] = f2bf(row[c2 * 36 + pp]);
  }
}

// ---------------------------------------------------------------------------
// Kernel 2: fused conv1+conv2 as 36 x (B/64) micro-GEMMs via MFMA.
// out2 layout: [B][k'] with k' = p*64 + c2.
// ---------------------------------------------------------------------------
#define LDP 72
__global__ __launch_bounds__(256) void conv_fused2(
    const float* __restrict__ x, const float* __restrict__ w1,
    const float* __restrict__ w2, unsigned short* __restrict__ out2, int B) {
  __shared__ unsigned short s_w2[64 * LDP];
  __shared__ unsigned short s_win[64 * LDP];
  const int tid = threadIdx.x;
  const int b0 = blockIdx.x * 64;
  const int p = blockIdx.y;
  const int u = p / 6, u2 = p % 6;

  const float* w2p = w2 + (size_t)p * 48;
  for (int i = tid; i < 64 * 64; i += 256) {
    int c2 = i >> 6, kk = i & 63;
    float v = (kk < 48) ? w2p[(size_t)c2 * 1728 + kk] : 0.f;
    s_w2[c2 * LDP + kk] = f2bf(v);
  }
  for (int i = tid; i < 64 * 64; i += 256) {
    int bi = i >> 6, kk = i & 63;
    float a = 0.f;
    if (kk < 48) {
      int c = kk >> 4, rem = kk & 15, v = rem >> 2, v2 = rem & 3;
      int pi = 2 * u + v, pj = 2 * u2 + v2;
      const float* wr = w1 + (((c * 196) + pi * 14 + pj) << 2);
      const float* xb = x + (size_t)(b0 + bi) * 784 + pi * 56 + pj * 2;
      a = fmaxf(xb[0] * wr[0] + xb[1] * wr[1] + xb[28] * wr[2] + xb[29] * wr[3],
                0.f);
    }
    s_win[bi * LDP + kk] = f2bf(a);
  }
  __syncthreads();

  const int lane = tid & 63, wave = tid >> 6;
  const int wm = wave >> 1, wn = wave & 1;
  const int fr = lane & 15, fo = (lane >> 4) * 8;
  f32x4 acc[2][2] = {};
  #pragma unroll
  for (int k2 = 0; k2 < 2; ++k2) {
    short8 af[2], bf[2];
    #pragma unroll
    for (int m = 0; m < 2; ++m)
      af[m] = *(const short8*)&s_win[(wm * 32 + m * 16 + fr) * LDP + k2 * 32 + fo];
    #pragma unroll
    for (int n = 0; n < 2; ++n)
      bf[n] = *(const short8*)&s_w2[(wn * 32 + n * 16 + fr) * LDP + k2 * 32 + fo];
    #pragma unroll
    for (int m = 0; m < 2; ++m)
      #pragma unroll
      for (int n = 0; n < 2; ++n)
        acc[m][n] =
            __builtin_amdgcn_mfma_f32_16x16x32_bf16(af[m], bf[n], acc[m][n], 0, 0, 0);
  }

  const int r0 = wm * 32 + (lane >> 4) * 4;
  const int c0 = wn * 32 + fr;
  #pragma unroll
  for (int m = 0; m < 2; ++m)
    #pragma unroll
    for (int n = 0; n < 2; ++n)
      #pragma unroll
      for (int j = 0; j < 4; ++j) {
        int bi = r0 + m * 16 + j;
        int c2 = c0 + n * 16;
        out2[(size_t)(b0 + bi) * 2304 + p * 64 + c2] =
            f2bf(fmaxf(acc[m][n][j], 0.f));
      }
}

// ---------------------------------------------------------------------------
// Kernel 3: fused  h = relu(out2 @ fc1b^T)  and  out += h @ fc2w^T.
// BM=BN=128, BK=64, 512 threads (8 waves 2x4, 64x32 out per wave).
// Double-buffered LDS, counted vmcnt(4), ONE barrier-pair per K-tile,
// T2 source-side XOR swizzle.  16 waves/CU (2 blocks) for latency hiding.
// ---------------------------------------------------------------------------
#define GBM 128
#define GBN 128
#define GBK 64

__global__ __launch_bounds__(512) void gemm_fc1_fc2(
    const unsigned short* __restrict__ A,   // [M][K] out2 bf16 (k' order)
    const unsigned short* __restrict__ Bw,  // [N][K] fc1b bf16 (k' order)
    const float* __restrict__ Wfc2,         // [10][1024] f32
    float* __restrict__ out,                // [M][10] f32 (pre-zeroed)
    int K, int NT) {
  __shared__ unsigned short sA[2 * GBM * GBK];  // 32 KiB
  __shared__ unsigned short sB[2 * GBN * GBK];  // 32 KiB
  __shared__ float sW[10 * GBN];                // 5 KiB
  const int tid = threadIdx.x;
  const int lane = tid & 63;
  const int wave = tid >> 6;
  const int wm = wave >> 2, wn = wave & 3;  // 2 x 4 wave grid, 64x32 each
  const size_t m0 = (size_t)blockIdx.x * GBM;
  const size_t n0 = (size_t)blockIdx.y * GBN;

  // --- staging geometry (T2: source-side XOR swizzle, linear LDS dest) ---
  const int r8 = tid >> 3;               // 0..63 (row within 64-row round)
  const int c8 = tid & 7;                // 16B chunk 0..7
  const int ksw = (c8 ^ (r8 & 7)) * 8;   // swizzled source k-chunk (elements)
  const unsigned short* Ag = A + (m0 + r8) * (size_t)K + ksw;
  const unsigned short* Bg = Bw + (n0 + r8) * (size_t)K + ksw;
  unsigned short* sAp = &sA[r8 * GBK + c8 * 8];
  unsigned short* sBp = &sB[r8 * GBK + c8 * 8];

#define STAGE_A(buf, t, i) \
  async_load16(Ag + (size_t)(t) * GBK + (size_t)(i) * 64 * K, \
               sAp + (buf) * (GBM * GBK) + (i) * 64 * GBK)
#define STAGE_B(buf, t, i) \
  async_load16(Bg + (size_t)(t) * GBK + (size_t)(i) * 64 * K, \
               sBp + (buf) * (GBN * GBK) + (i) * 64 * GBK)
#define STAGE_TILE(buf, t) \
  STAGE_A(buf, t, 0); STAGE_A(buf, t, 1); STAGE_B(buf, t, 0); STAGE_B(buf, t, 1)

  // prologue: tile 0 in flight (4 loads per wave)
  STAGE_TILE(0, 0);

  // --- fragment read geometry ---
  const int fr = lane & 15, fg = lane >> 4, fx = lane & 7;
  int aBase[4], bBase[2];
  #pragma unroll
  for (int m = 0; m < 4; ++m) aBase[m] = (wm * 64 + m * 16 + fr) * GBK;
  #pragma unroll
  for (int n = 0; n < 2; ++n) bBase[n] = (wn * 32 + n * 16 + fr) * GBK;
  const int jc0 = (fg ^ fx) * 8;  // ks=0 swizzled chunk offset (ushorts)
  const int jc1 = jc0 ^ 32;       // ks=1

  f32x4 acc[4][2] = {};

  for (int t = 0; t < NT; ++t) {
    const int cur = t & 1;
    if (t + 1 < NT) {
      STAGE_TILE(cur ^ 1, t + 1);                       // prefetch next tile
      asm volatile("s_waitcnt vmcnt(4)" ::: "memory");  // drain tile t only
    } else {
      asm volatile("s_waitcnt vmcnt(0)" ::: "memory");
    }
    __builtin_amdgcn_s_barrier();  // tile t visible to all waves

    const unsigned short* As = &sA[cur * GBM * GBK];
    const unsigned short* Bs = &sB[cur * GBN * GBK];
    short8 a0[4], a1[4], b0[2], b1[2];
    #pragma unroll
    for (int m = 0; m < 4; ++m) {
      a0[m] = *(const short8*)&As[aBase[m] + jc0];
      a1[m] = *(const short8*)&As[aBase[m] + jc1];
    }
    #pragma unroll
    for (int n = 0; n < 2; ++n) {
      b0[n] = *(const short8*)&Bs[bBase[n] + jc0];
      b1[n] = *(const short8*)&Bs[bBase[n] + jc1];
    }
    __builtin_amdgcn_s_setprio(1);
    #pragma unroll
    for (int m = 0; m < 4; ++m)
      #pragma unroll
      for (int n = 0; n < 2; ++n)
        acc[m][n] = __builtin_amdgcn_mfma_f32_16x16x32_bf16(a0[m], b0[n],
                                                            acc[m][n], 0, 0, 0);
    #pragma unroll
    for (int m = 0; m < 4; ++m)
      #pragma unroll
      for (int n = 0; n < 2; ++n)
        acc[m][n] = __builtin_amdgcn_mfma_f32_16x16x32_bf16(a1[m], b1[n],
                                                            acc[m][n], 0, 0, 0);
    __builtin_amdgcn_s_setprio(0);
    __builtin_amdgcn_s_barrier();  // all waves done reading buffer cur
  }

  // ---- stage fc2 weights now (outside the counted-vmcnt window) ----
  for (int i = tid; i < 10 * GBN; i += 512)
    sW[i] = Wfc2[(i >> 7) * 1024 + n0 + (i & 127)];

  // ---- epilogue: relu -> bf16 h-tile into LDS (swizzled), fused fc2 ----
  unsigned short* hs = sA;  // 128*128 ushorts = 32 KiB, staging is dead now
  #pragma unroll
  for (int m = 0; m < 4; ++m)
    #pragma unroll
    for (int n = 0; n < 2; ++n)
      #pragma unroll
      for (int j = 0; j < 4; ++j) {
        int row = wm * 64 + m * 16 + fg * 4 + j;  // 0..127
        int col = wn * 32 + n * 16 + fr;          // 0..127
        hs[row * 128 + (col ^ ((row & 7) << 3))] =
            f2bf(fmaxf(acc[m][n][j], 0.f));
      }
  __syncthreads();

  {
    const int row = tid >> 2;      // 0..127
    const int quar = tid & 3;      // 32-col quarter
    const int r7s = (row & 7) << 3;
    float hv[32];
    #pragma unroll
    for (int c = 0; c < 4; ++c) {
      int base = quar * 32 + c * 8;
      short8 u = *(const short8*)&hs[row * 128 + (base ^ r7s)];
      #pragma unroll
      for (int q = 0; q < 8; ++q) hv[c * 8 + q] = bf2f((unsigned short)u[q]);
    }
    float* op = out + (m0 + row) * 10;
    #pragma unroll
    for (int o = 0; o < 10; ++o) {
      const float* wr = &sW[o * 128 + quar * 32];
      float a = 0.f;
      #pragma unroll
      for (int q = 0; q < 32; ++q) a += hv[q] * wr[q];
      a += __shfl_down(a, 1);
      a += __shfl_down(a, 2);
      if (quar == 0) atomicAdd(&op[o], a);
    }
  }
#undef STAGE_A
#undef STAGE_B
#undef STAGE_TILE
}

// ---------------------------------------------------------------------------
extern "C" void kernel_launch(void* const* d_in, const int* in_sizes, int n_in,
                              void* d_out, int out_size, void* d_ws, size_t ws_size,
                              hipStream_t stream) {
  const float* x   = (const float*)d_in[0];
  const float* w1  = (const float*)d_in[1];
  const float* w2  = (const float*)d_in[2];
  const float* fc1 = (const float*)d_in[3];
  const float* fc2 = (const float*)d_in[4];
  float* out = (float*)d_out;
  const int B = in_sizes[0] / 784;  // 8192

  unsigned short* out2 = (unsigned short*)d_ws;       // B*2304 bf16
  unsigned short* fc1b = out2 + (size_t)B * 2304;     // 1024*2304 bf16

  hipMemsetAsync(out, 0, (size_t)out_size * sizeof(float), stream);
  cvt_permute<<<1024, 256, 0, stream>>>(fc1, fc1b);
  dim3 cg(B / 64, 36);
  conv_fused2<<<cg, 256, 0, stream>>>(x, w1, w2, out2, B);
  dim3 g(B / GBM, 1024 / GBN);
  gemm_fc1_fc2<<<g, 512, 0, stream>>>(out2, fc1b, fc2, out, 2304, 2304 / GBK);
}

// Round 6
// 102.640 us; speedup vs baseline: 1.5649x; 1.1634x over previous
//
#include <hip/hip_runtime.h>
#include <hip/hip_bf16.h>

typedef __attribute__((ext_vector_type(8))) short short8;
typedef __attribute__((ext_vector_type(4))) float f32x4;
typedef __attribute__((ext_vector_type(8))) unsigned short ushort8;
typedef __attribute__((ext_vector_type(4))) unsigned short ushort4v;

__device__ __forceinline__ float bf2f(unsigned short u) {
  union { unsigned int i; float f; } v;
  v.i = ((unsigned int)u) << 16;
  return v.f;
}

__device__ __forceinline__ unsigned short f2bf(float f) {
  union { float f; unsigned int i; } v;
  v.f = f;
  unsigned int x = v.i;
  return (unsigned short)((x + 0x7FFFu + ((x >> 16) & 1u)) >> 16);
}

__device__ __forceinline__ void async_load16(const void* g, void* l) {
  __builtin_amdgcn_global_load_lds(
      (const __attribute__((address_space(1))) unsigned int*)g,
      (__attribute__((address_space(3))) unsigned int*)l, 16, 0, 0);
}

// ---------------------------------------------------------------------------
// Kernel 1: fc1w f32 -> bf16 with k-permutation k' = p*64 + c2  (k = c2*36+p)
// ---------------------------------------------------------------------------
__global__ __launch_bounds__(256) void cvt_permute(
    const float* __restrict__ fc1, unsigned short* __restrict__ out) {
  __shared__ float row[2304];
  const int n = blockIdx.x;
  const float* src = fc1 + (size_t)n * 2304;
  for (int i = threadIdx.x; i < 2304; i += 256) row[i] = src[i];
  __syncthreads();
  unsigned short* dst = out + (size_t)n * 2304;
  for (int i = threadIdx.x; i < 2304; i += 256) {
    int pp = i >> 6, c2 = i & 63;
    dst[i] = f2bf(row[c2 * 36 + pp]);
  }
}

// ---------------------------------------------------------------------------
// Kernel 2: fused conv1+conv2 as 36 x (B/64) micro-GEMMs via MFMA.
// out2 layout: [B][k'] with k' = p*64 + c2.
// Vectorized float4 loads, LDS-restaged coalesced 16B stores.
// ---------------------------------------------------------------------------
#define LDP 72
__global__ __launch_bounds__(256) void conv_fused3(
    const float* __restrict__ x, const float* __restrict__ w1,
    const float* __restrict__ w2, unsigned short* __restrict__ out2, int B) {
  __shared__ unsigned short s_w2[64 * LDP];
  __shared__ unsigned short s_win[64 * LDP];
  const int tid = threadIdx.x;
  const int b0 = blockIdx.x * 64;
  const int p = blockIdx.y;  // 0..35
  const int u = p / 6, u2 = p % 6;

  // --- stage w2 slice [c2][48] -> bf16, float4-vectorized (3 items/thread)
  {
    const float* w2p = w2 + (size_t)p * 48;
    for (int it = tid; it < 768; it += 256) {
      int c2 = it & 63, q = it >> 6;  // q = 0..11 (4-element chunk)
      float4 wv = *(const float4*)(w2p + (size_t)c2 * 1728 + 4 * q);
      ushort4v o;
      o[0] = f2bf(wv.x); o[1] = f2bf(wv.y); o[2] = f2bf(wv.z); o[3] = f2bf(wv.w);
      *(ushort4v*)&s_w2[c2 * LDP + 4 * q] = o;
    }
  }

  // --- win[bi][16c+4v+v2] via float4 patch loads (3 items/thread) ---
  for (int it = tid; it < 768; it += 256) {
    int bi = it & 63, cv = it >> 6;   // cv = c*4+v
    int c = cv >> 2, v = cv & 3;
    int pi = 2 * u + v;
    const float* xb = x + (size_t)(b0 + bi) * 784 + pi * 56 + 4 * u2;
    float4 a0 = *(const float4*)xb;
    float4 a1 = *(const float4*)(xb + 4);
    float4 r0 = *(const float4*)(xb + 28);
    float4 r1 = *(const float4*)(xb + 32);
    const float* wbase = w1 + ((c * 196 + pi * 14 + 2 * u2) << 2);
    float4 q0 = *(const float4*)(wbase);
    float4 q1 = *(const float4*)(wbase + 4);
    float4 q2 = *(const float4*)(wbase + 8);
    float4 q3 = *(const float4*)(wbase + 12);
    ushort4v o;
    o[0] = f2bf(fmaxf(a0.x * q0.x + a0.y * q0.y + r0.x * q0.z + r0.y * q0.w, 0.f));
    o[1] = f2bf(fmaxf(a0.z * q1.x + a0.w * q1.y + r0.z * q1.z + r0.w * q1.w, 0.f));
    o[2] = f2bf(fmaxf(a1.x * q2.x + a1.y * q2.y + r1.x * q2.z + r1.y * q2.w, 0.f));
    o[3] = f2bf(fmaxf(a1.z * q3.x + a1.w * q3.y + r1.z * q3.z + r1.w * q3.w, 0.f));
    *(ushort4v*)&s_win[bi * LDP + 4 * cv] = o;
  }

  // --- zero-pad k = 48..63 for both tiles (1 item/thread) ---
  {
    int bi = tid >> 2, q = tid & 3;
    ushort4v z = {0, 0, 0, 0};
    *(ushort4v*)&s_win[bi * LDP + 48 + 4 * q] = z;
    *(ushort4v*)&s_w2[bi * LDP + 48 + 4 * q] = z;
  }
  __syncthreads();

  // --- micro-GEMM: C[bi][c2] = win @ w2^T, 16x16x32 MFMA, waves 2x2 of 32x32
  const int lane = tid & 63, wave = tid >> 6;
  const int wm = wave >> 1, wn = wave & 1;
  const int fr = lane & 15, fo = (lane >> 4) * 8;
  f32x4 acc[2][2] = {};
  #pragma unroll
  for (int k2 = 0; k2 < 2; ++k2) {
    short8 af[2], bf[2];
    #pragma unroll
    for (int m = 0; m < 2; ++m)
      af[m] = *(const short8*)&s_win[(wm * 32 + m * 16 + fr) * LDP + k2 * 32 + fo];
    #pragma unroll
    for (int n = 0; n < 2; ++n)
      bf[n] = *(const short8*)&s_w2[(wn * 32 + n * 16 + fr) * LDP + k2 * 32 + fo];
    #pragma unroll
    for (int m = 0; m < 2; ++m)
      #pragma unroll
      for (int n = 0; n < 2; ++n)
        acc[m][n] =
            __builtin_amdgcn_mfma_f32_16x16x32_bf16(af[m], bf[n], acc[m][n], 0, 0, 0);
  }
  __syncthreads();  // all frag reads done; s_win reusable as output stage

  // --- restage result tile [bi][c2] in LDS, then coalesced 16B stores ---
  unsigned short* s_out = s_win;
  const int r0 = wm * 32 + (lane >> 4) * 4;
  const int c0 = wn * 32 + fr;
  #pragma unroll
  for (int m = 0; m < 2; ++m)
    #pragma unroll
    for (int n = 0; n < 2; ++n)
      #pragma unroll
      for (int j = 0; j < 4; ++j)
        s_out[(r0 + m * 16 + j) * 64 + (c0 + n * 16)] =
            f2bf(fmaxf(acc[m][n][j], 0.f));
  __syncthreads();

  for (int it = tid; it < 512; it += 256) {
    int row = it >> 3, ch = it & 7;
    *(short8*)(out2 + (size_t)(b0 + row) * 2304 + p * 64 + ch * 8) =
        *(const short8*)&s_out[row * 64 + ch * 8];
  }
}

// ---------------------------------------------------------------------------
// Kernel 3: fused  h = relu(out2 @ fc1b^T)  and  out += h @ fc2w^T.
// BM=BN=128, BK=64, 512 threads (8 waves 2x4, 64x32 out per wave).
// Double-buffered LDS, counted vmcnt(4), ONE barrier-pair per K-tile,
// T2 source-side XOR swizzle.
// ---------------------------------------------------------------------------
#define GBM 128
#define GBN 128
#define GBK 64

__global__ __launch_bounds__(512) void gemm_fc1_fc2(
    const unsigned short* __restrict__ A,   // [M][K] out2 bf16 (k' order)
    const unsigned short* __restrict__ Bw,  // [N][K] fc1b bf16 (k' order)
    const float* __restrict__ Wfc2,         // [10][1024] f32
    float* __restrict__ out,                // [M][10] f32 (pre-zeroed)
    int K, int NT) {
  __shared__ unsigned short sA[2 * GBM * GBK];  // 32 KiB
  __shared__ unsigned short sB[2 * GBN * GBK];  // 32 KiB
  __shared__ float sW[10 * GBN];                // 5 KiB
  const int tid = threadIdx.x;
  const int lane = tid & 63;
  const int wave = tid >> 6;
  const int wm = wave >> 2, wn = wave & 3;  // 2 x 4 wave grid, 64x32 each
  const size_t m0 = (size_t)blockIdx.x * GBM;
  const size_t n0 = (size_t)blockIdx.y * GBN;

  const int r8 = tid >> 3;               // 0..63
  const int c8 = tid & 7;                // 16B chunk 0..7
  const int ksw = (c8 ^ (r8 & 7)) * 8;   // swizzled source k-chunk
  const unsigned short* Ag = A + (m0 + r8) * (size_t)K + ksw;
  const unsigned short* Bg = Bw + (n0 + r8) * (size_t)K + ksw;
  unsigned short* sAp = &sA[r8 * GBK + c8 * 8];
  unsigned short* sBp = &sB[r8 * GBK + c8 * 8];

#define STAGE_A(buf, t, i) \
  async_load16(Ag + (size_t)(t) * GBK + (size_t)(i) * 64 * K, \
               sAp + (buf) * (GBM * GBK) + (i) * 64 * GBK)
#define STAGE_B(buf, t, i) \
  async_load16(Bg + (size_t)(t) * GBK + (size_t)(i) * 64 * K, \
               sBp + (buf) * (GBN * GBK) + (i) * 64 * GBK)
#define STAGE_TILE(buf, t) \
  STAGE_A(buf, t, 0); STAGE_A(buf, t, 1); STAGE_B(buf, t, 0); STAGE_B(buf, t, 1)

  STAGE_TILE(0, 0);

  const int fr = lane & 15, fg = lane >> 4, fx = lane & 7;
  int aBase[4], bBase[2];
  #pragma unroll
  for (int m = 0; m < 4; ++m) aBase[m] = (wm * 64 + m * 16 + fr) * GBK;
  #pragma unroll
  for (int n = 0; n < 2; ++n) bBase[n] = (wn * 32 + n * 16 + fr) * GBK;
  const int jc0 = (fg ^ fx) * 8;
  const int jc1 = jc0 ^ 32;

  f32x4 acc[4][2] = {};

  for (int t = 0; t < NT; ++t) {
    const int cur = t & 1;
    if (t + 1 < NT) {
      STAGE_TILE(cur ^ 1, t + 1);
      asm volatile("s_waitcnt vmcnt(4)" ::: "memory");
    } else {
      asm volatile("s_waitcnt vmcnt(0)" ::: "memory");
    }
    __builtin_amdgcn_s_barrier();

    const unsigned short* As = &sA[cur * GBM * GBK];
    const unsigned short* Bs = &sB[cur * GBN * GBK];
    short8 a0[4], a1[4], b0[2], b1[2];
    #pragma unroll
    for (int m = 0; m < 4; ++m) {
      a0[m] = *(const short8*)&As[aBase[m] + jc0];
      a1[m] = *(const short8*)&As[aBase[m] + jc1];
    }
    #pragma unroll
    for (int n = 0; n < 2; ++n) {
      b0[n] = *(const short8*)&Bs[bBase[n] + jc0];
      b1[n] = *(const short8*)&Bs[bBase[n] + jc1];
    }
    __builtin_amdgcn_s_setprio(1);
    #pragma unroll
    for (int m = 0; m < 4; ++m)
      #pragma unroll
      for (int n = 0; n < 2; ++n)
        acc[m][n] = __builtin_amdgcn_mfma_f32_16x16x32_bf16(a0[m], b0[n],
                                                            acc[m][n], 0, 0, 0);
    #pragma unroll
    for (int m = 0; m < 4; ++m)
      #pragma unroll
      for (int n = 0; n < 2; ++n)
        acc[m][n] = __builtin_amdgcn_mfma_f32_16x16x32_bf16(a1[m], b1[n],
                                                            acc[m][n], 0, 0, 0);
    __builtin_amdgcn_s_setprio(0);
    __builtin_amdgcn_s_barrier();
  }

  for (int i = tid; i < 10 * GBN; i += 512)
    sW[i] = Wfc2[(i >> 7) * 1024 + n0 + (i & 127)];

  unsigned short* hs = sA;
  #pragma unroll
  for (int m = 0; m < 4; ++m)
    #pragma unroll
    for (int n = 0; n < 2; ++n)
      #pragma unroll
      for (int j = 0; j < 4; ++j) {
        int row = wm * 64 + m * 16 + fg * 4 + j;
        int col = wn * 32 + n * 16 + fr;
        hs[row * 128 + (col ^ ((row & 7) << 3))] =
            f2bf(fmaxf(acc[m][n][j], 0.f));
      }
  __syncthreads();

  {
    const int row = tid >> 2;
    const int quar = tid & 3;
    const int r7s = (row & 7) << 3;
    float hv[32];
    #pragma unroll
    for (int c = 0; c < 4; ++c) {
      int base = quar * 32 + c * 8;
      short8 u = *(const short8*)&hs[row * 128 + (base ^ r7s)];
      #pragma unroll
      for (int q = 0; q < 8; ++q) hv[c * 8 + q] = bf2f((unsigned short)u[q]);
    }
    float* op = out + (m0 + row) * 10;
    #pragma unroll
    for (int o = 0; o < 10; ++o) {
      const float* wr = &sW[o * 128 + quar * 32];
      float a = 0.f;
      #pragma unroll
      for (int q = 0; q < 32; ++q) a += hv[q] * wr[q];
      a += __shfl_down(a, 1);
      a += __shfl_down(a, 2);
      if (quar == 0) atomicAdd(&op[o], a);
    }
  }
#undef STAGE_A
#undef STAGE_B
#undef STAGE_TILE
}

// ---------------------------------------------------------------------------
extern "C" void kernel_launch(void* const* d_in, const int* in_sizes, int n_in,
                              void* d_out, int out_size, void* d_ws, size_t ws_size,
                              hipStream_t stream) {
  const float* x   = (const float*)d_in[0];
  const float* w1  = (const float*)d_in[1];
  const float* w2  = (const float*)d_in[2];
  const float* fc1 = (const float*)d_in[3];
  const float* fc2 = (const float*)d_in[4];
  float* out = (float*)d_out;
  const int B = in_sizes[0] / 784;  // 8192

  unsigned short* out2 = (unsigned short*)d_ws;       // B*2304 bf16
  unsigned short* fc1b = out2 + (size_t)B * 2304;     // 1024*2304 bf16

  hipMemsetAsync(out, 0, (size_t)out_size * sizeof(float), stream);
  cvt_permute<<<1024, 256, 0, stream>>>(fc1, fc1b);
  dim3 cg(B / 64, 36);
  conv_fused3<<<cg, 256, 0, stream>>>(x, w1, w2, out2, B);
  dim3 g(B / GBM, 1024 / GBN);
  gemm_fc1_fc2<<<g, 512, 0, stream>>>(out2, fc1b, fc2, out, 2304, 2304 / GBK);
}